// Round 11
// baseline (361.746 us; speedup 1.0000x reference)
//
#include <hip/hip_runtime.h>
#include <math.h>

// HashGrid: 8 LODs, hashed trilinear interp, 1 feature/entry, summed over LODs.
// LODS  = [17, 27, 44, 71, 116, 191, 313, res7(host-computed, 512 or 513)]
// SIZES = [4913, 19683, 85184, 357911, 2^19, 2^19, 2^19, 2^19]
// codebook layout: [8][524288][1] float32.
//
// R11: wall = gather-request throughput (~0.37 lane-req/cyc/CU, R2-R10).
// Extend the x-pair dword merge to ALL global LODs:
//  - pow2 (4..7): E=(h&~1)&m even -> aligned dword in u16 table   [R10]
//  - LOD2 size 85184 even: E=(h&~1)%size is EVEN -> aligned dword [free]
//  - LOD3 size 357911 odd: paired dword table T2[k]=(T[k],T[(k+1)%size])
//    (+1.43 MB ws) -> one dword at T2[E]                          [new]
// Requests/pt: 16 LDS + 6x6 global = 36 (was 40).

static constexpr unsigned CB_STRIDE = 524288u;
static constexpr int S0 = 4913;    // 17^3
static constexpr int S1 = 19683;   // 27^3
// ws (bf16) element offsets for LOD2..7 (all EVEN -> dword pairing valid)
static constexpr unsigned WO2 = 0;        // 85184
static constexpr unsigned WO3 = 85184;    // 357911
static constexpr unsigned WO4 = 443104;   // 524288
static constexpr unsigned WO5 = 967392;
static constexpr unsigned WO6 = 1491680;
static constexpr unsigned WO7 = 2015968;  // -> end 2540256 u16 = 5080512 B
static constexpr unsigned PAIR3_BYTE_OFF = 5080512u;        // 4-aligned
static constexpr unsigned PAIR3_COUNT = 357911u;            // dwords
static constexpr size_t WS_NEED_BYTES = 5080512u + PAIR3_COUNT * 4u;  // 6.51 MB

__device__ __forceinline__ unsigned short f32_to_bf16_rne(float f) {
    unsigned u = __float_as_uint(f);
    u = (u + 0x7FFFu + ((u >> 16) & 1u)) >> 16;
    return (unsigned short)u;
}
__device__ __forceinline__ float bf16_to_f32(unsigned short s) {
    return __uint_as_float(((unsigned)s) << 16);
}

struct I8 { unsigned a0, a1, a2, a3, a4, a5, a6, a7; };
struct R8 { unsigned short v0, v1, v2, v3, v4, v5, v6, v7; };
struct W3 { float x, y, z; };

template <unsigned SIZE>
__device__ __forceinline__ I8 idx8m(float p01x, float p01y, float p01z, int res, W3& fr)
{
    const float rm1 = (float)(res - 1);
    float xx = p01x * rm1, yy = p01y * rm1, zz = p01z * rm1;
    const float cmax = (float)(res - 2);
    float fx = fminf(fmaxf(floorf(xx), 0.0f), cmax);
    float fy = fminf(fmaxf(floorf(yy), 0.0f), cmax);
    float fz = fminf(fmaxf(floorf(zz), 0.0f), cmax);
    fr.x = xx - fx; fr.y = yy - fy; fr.z = zz - fz;
    const unsigned ix = (unsigned)(int)fx;
    const unsigned iy = (unsigned)(int)fy;
    const unsigned iz = (unsigned)(int)fz;
    const unsigned hy0 = iy * 2654435761u, hy1 = hy0 + 2654435761u;
    const unsigned hz0 = iz * 805459861u,  hz1 = hz0 + 805459861u;
    I8 o;
    o.a0 = (ix ^ hy0 ^ hz0) % SIZE;        o.a1 = (ix ^ hy0 ^ hz1) % SIZE;
    o.a2 = (ix ^ hy1 ^ hz0) % SIZE;        o.a3 = (ix ^ hy1 ^ hz1) % SIZE;
    o.a4 = ((ix+1u) ^ hy0 ^ hz0) % SIZE;   o.a5 = ((ix+1u) ^ hy0 ^ hz1) % SIZE;
    o.a6 = ((ix+1u) ^ hy1 ^ hz0) % SIZE;   o.a7 = ((ix+1u) ^ hy1 ^ hz1) % SIZE;
    return o;
}

__device__ __forceinline__ R8 gather8(const unsigned short* __restrict__ t, I8 o)
{
    R8 r;
    r.v0 = t[o.a0]; r.v1 = t[o.a1]; r.v2 = t[o.a2]; r.v3 = t[o.a3];
    r.v4 = t[o.a4]; r.v5 = t[o.a5]; r.v6 = t[o.a6]; r.v7 = t[o.a7];
    return r;
}

__device__ __forceinline__ float acc8(R8 r, W3 f)
{
    const float wx1 = f.x, wx0 = 1.0f - f.x;
    const float wy1 = f.y, wy0 = 1.0f - f.y;
    const float wz1 = f.z, wz0 = 1.0f - f.z;
    const float w00 = wy0 * wz0, w01 = wy0 * wz1;
    const float w10 = wy1 * wz0, w11 = wy1 * wz1;
    const float sx0 = bf16_to_f32(r.v0) * w00 + bf16_to_f32(r.v1) * w01
                    + bf16_to_f32(r.v2) * w10 + bf16_to_f32(r.v3) * w11;
    const float sx1 = bf16_to_f32(r.v4) * w00 + bf16_to_f32(r.v5) * w01
                    + bf16_to_f32(r.v6) * w10 + bf16_to_f32(r.v7) * w11;
    return wx0 * sx0 + wx1 * sx1;
}

// Merged x-pair LOD. MODE: 0 = pow2 2^19 (mask), 1 = mod 85184 (even size,
// inline dwords), 2 = mod 357911 (odd size, separate pair table).
// t = u16 table base (for odd-ix x1 loads; MODE0/1 also for pair dwords).
template <int MODE>
__device__ __forceinline__ float lod_merged(float p01x, float p01y, float p01z,
                                            int res,
                                            const unsigned short* __restrict__ t,
                                            const unsigned* __restrict__ pair3)
{
    const float rm1 = (float)(res - 1);
    float xx = p01x * rm1, yy = p01y * rm1, zz = p01z * rm1;
    const float cmax = (float)(res - 2);
    float fx = fminf(fmaxf(floorf(xx), 0.0f), cmax);
    float fy = fminf(fmaxf(floorf(yy), 0.0f), cmax);
    float fz = fminf(fmaxf(floorf(zz), 0.0f), cmax);
    const float frx = xx - fx, fry = yy - fy, frz = zz - fz;
    const unsigned ix = (unsigned)(int)fx;
    const unsigned iy = (unsigned)(int)fy;
    const unsigned iz = (unsigned)(int)fz;

    const unsigned hy0 = iy * 2654435761u, hy1 = hy0 + 2654435761u;
    const unsigned hz0 = iz * 805459861u,  hz1 = hz0 + 805459861u;

    const unsigned h00 = ix ^ hy0 ^ hz0;
    const unsigned h01 = ix ^ hy0 ^ hz1;
    const unsigned h10 = ix ^ hy1 ^ hz0;
    const unsigned h11 = ix ^ hy1 ^ hz1;

    // even base -> pair element index E (consecutive {E,E+1} covers x-pair)
    unsigned E00, E01, E10, E11;
    if (MODE == 0) {
        const unsigned bm = 524286u;  // (2^19-1) & ~1
        E00 = h00 & bm; E01 = h01 & bm; E10 = h10 & bm; E11 = h11 & bm;
    } else if (MODE == 1) {
        E00 = (h00 & ~1u) % 85184u; E01 = (h01 & ~1u) % 85184u;
        E10 = (h10 & ~1u) % 85184u; E11 = (h11 & ~1u) % 85184u;
    } else {
        E00 = (h00 & ~1u) % 357911u; E01 = (h01 & ~1u) % 357911u;
        E10 = (h10 & ~1u) % 357911u; E11 = (h11 & ~1u) % 357911u;
    }

    unsigned p00, p01, p10, p11;
    if (MODE == 2) {
        p00 = pair3[E00]; p01 = pair3[E01]; p10 = pair3[E10]; p11 = pair3[E11];
    } else {
        const unsigned* t32 = reinterpret_cast<const unsigned*>(t);  // t 4B-aligned, E even
        p00 = t32[E00 >> 1]; p01 = t32[E01 >> 1]; p10 = t32[E10 >> 1]; p11 = t32[E11 >> 1];
    }

    const bool oddx = (ix & 1u) != 0u;
    unsigned short q00 = 0, q01 = 0, q10 = 0, q11 = 0;
    if (oddx) {
        const unsigned g = ix + 1u;
        if (MODE == 0) {
            const unsigned m = 524287u;
            q00 = t[(g ^ hy0 ^ hz0) & m]; q01 = t[(g ^ hy0 ^ hz1) & m];
            q10 = t[(g ^ hy1 ^ hz0) & m]; q11 = t[(g ^ hy1 ^ hz1) & m];
        } else if (MODE == 1) {
            q00 = t[(g ^ hy0 ^ hz0) % 85184u]; q01 = t[(g ^ hy0 ^ hz1) % 85184u];
            q10 = t[(g ^ hy1 ^ hz0) % 85184u]; q11 = t[(g ^ hy1 ^ hz1) % 85184u];
        } else {
            q00 = t[(g ^ hy0 ^ hz0) % 357911u]; q01 = t[(g ^ hy0 ^ hz1) % 357911u];
            q10 = t[(g ^ hy1 ^ hz0) % 357911u]; q11 = t[(g ^ hy1 ^ hz1) % 357911u];
        }
    }

    const unsigned s00 = h00 & 1u, s01 = h01 & 1u, s10 = h10 & 1u, s11 = h11 & 1u;
    const float a00 = bf16_to_f32((unsigned short)(s00 ? (p00 >> 16) : (p00 & 0xffffu)));
    const float a01 = bf16_to_f32((unsigned short)(s01 ? (p01 >> 16) : (p01 & 0xffffu)));
    const float a10 = bf16_to_f32((unsigned short)(s10 ? (p10 >> 16) : (p10 & 0xffffu)));
    const float a11 = bf16_to_f32((unsigned short)(s11 ? (p11 >> 16) : (p11 & 0xffffu)));
    const float b00 = bf16_to_f32(oddx ? q00 : (unsigned short)(s00 ? (p00 & 0xffffu) : (p00 >> 16)));
    const float b01 = bf16_to_f32(oddx ? q01 : (unsigned short)(s01 ? (p01 & 0xffffu) : (p01 >> 16)));
    const float b10 = bf16_to_f32(oddx ? q10 : (unsigned short)(s10 ? (p10 & 0xffffu) : (p10 >> 16)));
    const float b11 = bf16_to_f32(oddx ? q11 : (unsigned short)(s11 ? (p11 & 0xffffu) : (p11 >> 16)));

    const float wx1 = frx, wx0 = 1.0f - frx;
    const float wy1 = fry, wy0 = 1.0f - fry;
    const float wz1 = frz, wz0 = 1.0f - frz;
    const float w00 = wy0 * wz0, w01 = wy0 * wz1;
    const float w10 = wy1 * wz0, w11 = wy1 * wz1;
    const float sx0 = a00 * w00 + a01 * w01 + a10 * w10 + a11 * w11;
    const float sx1 = b00 * w00 + b01 * w01 + b10 * w10 + b11 * w11;
    return wx0 * sx0 + wx1 * sx1;
}

// prep: bf16 tables for LOD2..7 + paired dword table for LOD3
__global__ __launch_bounds__(1024)
void HashGrid_convert_kernel(const float* __restrict__ codebook,
                             unsigned short* __restrict__ ws)
{
    const int job = blockIdx.y;  // 0..5 -> LOD2..7 u16; 6 -> LOD3 pair table
    const int idx = blockIdx.x * 1024 + threadIdx.x;
    if (job < 6) {
        const int sizes[6] = {85184, 357911, 524288, 524288, 524288, 524288};
        const unsigned offs[6] = {WO2, WO3, WO4, WO5, WO6, WO7};
        if (idx < sizes[job])
            ws[offs[job] + idx] = f32_to_bf16_rne(codebook[(unsigned)(job + 2) * CB_STRIDE + idx]);
    } else {
        if (idx < (int)PAIR3_COUNT) {
            const float* t3 = codebook + 3u * CB_STRIDE;
            const unsigned lo = f32_to_bf16_rne(t3[idx]);
            const unsigned hi = f32_to_bf16_rne(t3[(idx + 1u) % PAIR3_COUNT]);
            unsigned* pair3 = (unsigned*)((char*)ws + PAIR3_BYTE_OFF);
            pair3[idx] = lo | (hi << 16);
        }
    }
}

__global__ __launch_bounds__(1024, 4)
void HashGrid_88278757802387_kernel(const float* __restrict__ pts,
                                    const float* __restrict__ codebook,
                                    const unsigned short* __restrict__ ws,
                                    float* __restrict__ out,
                                    int n, int res7)
{
    __shared__ unsigned short sm[S0 + S1];  // 49.2 KB
    for (int j = threadIdx.x; j < S0 + S1; j += 1024)
        sm[j] = f32_to_bf16_rne(j < S0 ? codebook[j] : codebook[CB_STRIDE + (j - S0)]);
    __syncthreads();

    const int i = blockIdx.x * 1024 + threadIdx.x;
    if (i >= n) return;

    const float p01x = pts[3 * i + 0] * 0.5f + 0.5f;
    const float p01y = pts[3 * i + 1] * 0.5f + 0.5f;
    const float p01z = pts[3 * i + 2] * 0.5f + 0.5f;

    const unsigned* pair3 = (const unsigned*)((const char*)ws + PAIR3_BYTE_OFF);

    // global LODs, all merged x-pair (6 avg requests each)
    float acc = lod_merged<1>(p01x, p01y, p01z, 44,   ws + WO2, pair3);
    acc      += lod_merged<2>(p01x, p01y, p01z, 71,   ws + WO3, pair3);
    acc      += lod_merged<0>(p01x, p01y, p01z, 116,  ws + WO4, pair3);
    acc      += lod_merged<0>(p01x, p01y, p01z, 191,  ws + WO5, pair3);
    acc      += lod_merged<0>(p01x, p01y, p01z, 313,  ws + WO6, pair3);
    acc      += lod_merged<0>(p01x, p01y, p01z, res7, ws + WO7, pair3);

    // LDS LODs (off the TCP path)
    W3 fL0, fL1;
    I8 oL0 = idx8m<4913u >(p01x, p01y, p01z, 17, fL0);
    I8 oL1 = idx8m<19683u>(p01x, p01y, p01z, 27, fL1);
    R8 rL0 = gather8(sm, oL0);
    R8 rL1 = gather8(sm + S0, oL1);
    acc += acc8(rL0, fL0) + acc8(rL1, fL1);

    out[i] = acc;
}

// fallback (no ws): per-LOD f32 path straight from codebook
__global__ __launch_bounds__(1024, 4)
void HashGrid_fallback_kernel(const float* __restrict__ pts,
                              const float* __restrict__ codebook,
                              float* __restrict__ out,
                              int n, int res7)
{
    const int i = blockIdx.x * 1024 + threadIdx.x;
    if (i >= n) return;
    const float p01x = pts[3 * i + 0] * 0.5f + 0.5f;
    const float p01y = pts[3 * i + 1] * 0.5f + 0.5f;
    const float p01z = pts[3 * i + 2] * 0.5f + 0.5f;
    float acc = 0.0f;
    const int      reslist[8]  = {17, 27, 44, 71, 116, 191, 313, res7};
    const unsigned sizelist[8] = {4913u, 19683u, 85184u, 357911u, 524288u, 524288u, 524288u, 524288u};
    for (int l = 0; l < 8; ++l) {
        const int res = reslist[l];
        const unsigned size = sizelist[l];
        const float rm1 = (float)(res - 1);
        float xx = p01x * rm1, yy = p01y * rm1, zz = p01z * rm1;
        float fx = fminf(fmaxf(floorf(xx), 0.0f), (float)(res - 2));
        float fy = fminf(fmaxf(floorf(yy), 0.0f), (float)(res - 2));
        float fz = fminf(fmaxf(floorf(zz), 0.0f), (float)(res - 2));
        const float frx = xx - fx, fry = yy - fy, frz = zz - fz;
        const unsigned ix = (unsigned)(int)fx, iy = (unsigned)(int)fy, iz = (unsigned)(int)fz;
        const unsigned hy0 = iy * 2654435761u, hy1 = hy0 + 2654435761u;
        const unsigned hz0 = iz * 805459861u,  hz1 = hz0 + 805459861u;
        const unsigned o0 = (ix ^ hy0 ^ hz0) % size,      o1 = (ix ^ hy0 ^ hz1) % size;
        const unsigned o2 = (ix ^ hy1 ^ hz0) % size,      o3 = (ix ^ hy1 ^ hz1) % size;
        const unsigned o4 = ((ix+1u) ^ hy0 ^ hz0) % size, o5 = ((ix+1u) ^ hy0 ^ hz1) % size;
        const unsigned o6 = ((ix+1u) ^ hy1 ^ hz0) % size, o7 = ((ix+1u) ^ hy1 ^ hz1) % size;
        const float* tab = codebook + (unsigned)l * CB_STRIDE;
        const float wx1 = frx, wx0 = 1.0f - frx;
        const float wy1 = fry, wy0 = 1.0f - fry;
        const float wz1 = frz, wz0 = 1.0f - frz;
        const float w00 = wy0*wz0, w01 = wy0*wz1, w10 = wy1*wz0, w11 = wy1*wz1;
        acc += wx0 * (tab[o0]*w00 + tab[o1]*w01 + tab[o2]*w10 + tab[o3]*w11)
             + wx1 * (tab[o4]*w00 + tab[o5]*w01 + tab[o6]*w10 + tab[o7]*w11);
    }
    out[i] = acc;
}

extern "C" void kernel_launch(void* const* d_in, const int* in_sizes, int n_in,
                              void* d_out, int out_size, void* d_ws, size_t ws_size,
                              hipStream_t stream)
{
    const float* pts      = (const float*)d_in[0];
    const float* codebook = (const float*)d_in[1];
    float* out            = (float*)d_out;
    const int n = in_sizes[0] / 3;

    // numpy-matching LOD7 resolution (16*b^7 sits ~1e-12 from 512.0)
    const double b = exp((log(512.0) - log(16.0)) / 7.0);
    const int res7 = (int)(1.0 + floor(16.0 * pow(b, 7.0)));

    const bool use_ws = (d_ws != nullptr) && (ws_size >= WS_NEED_BYTES);
    const int blocks = (n + 1023) / 1024;

    if (use_ws) {
        unsigned short* ws = (unsigned short*)d_ws;
        hipLaunchKernelGGL(HashGrid_convert_kernel, dim3(512, 7), dim3(1024),
                           0, stream, codebook, ws);
        hipLaunchKernelGGL(HashGrid_88278757802387_kernel, dim3(blocks), dim3(1024),
                           0, stream, pts, codebook, ws, out, n, res7);
    } else {
        hipLaunchKernelGGL(HashGrid_fallback_kernel, dim3(blocks), dim3(1024),
                           0, stream, pts, codebook, out, n, res7);
    }
}

// Round 12
// 353.149 us; speedup vs baseline: 1.0243x; 1.0243x over previous
//
#include <hip/hip_runtime.h>
#include <math.h>

// HashGrid: 8 LODs, hashed trilinear interp, 1 feature/entry, summed over LODs.
// LODS  = [17, 27, 44, 71, 116, 191, 313, res7(host-computed, 512 or 513)]
// SIZES = [4913, 19683, 85184, 357911, 2^19, 2^19, 2^19, 2^19]
// codebook layout: [8][524288][1] float32.
//
// R12: refined model -- dur ~ requests/pt / rate(footprint); rate degrades
// when gather footprint exceeds the 4MB per-XCD L2 (R11: +1.4MB pair table
// -> FETCH +44%, net loss). Keep only footprint-free request cuts:
//  - LOD0/1 in LDS (16 req off TCP path)
//  - LOD2 (size 85184 EVEN): inline x-pair dword merge in the existing u16
//    table: E=(h&~1)%85184 is even -> aligned dword. 6 avg req, 0 extra B.
//  - LOD4..7 pow2: x-pair merge (R10). 6 avg req each.
//  - LOD3 (odd size): plain 8 u16 gathers, issued early.
// 38 req/pt at R10's exact 5.08MB footprint.

static constexpr unsigned CB_STRIDE = 524288u;
static constexpr int S0 = 4913;    // 17^3
static constexpr int S1 = 19683;   // 27^3
// ws (bf16) element offsets for LOD2..7 (all EVEN, tables 4B-aligned)
static constexpr unsigned WO2 = 0;        // 85184
static constexpr unsigned WO3 = 85184;    // 357911
static constexpr unsigned WO4 = 443104;   // 524288
static constexpr unsigned WO5 = 967392;
static constexpr unsigned WO6 = 1491680;
static constexpr unsigned WO7 = 2015968;  // -> end 2540256 u16
static constexpr size_t WS_NEED_BYTES = 2540256u * 2u;  // 5.08 MB

__device__ __forceinline__ unsigned short f32_to_bf16_rne(float f) {
    unsigned u = __float_as_uint(f);
    u = (u + 0x7FFFu + ((u >> 16) & 1u)) >> 16;
    return (unsigned short)u;
}
__device__ __forceinline__ float bf16_to_f32(unsigned short s) {
    return __uint_as_float(((unsigned)s) << 16);
}

struct I8 { unsigned a0, a1, a2, a3, a4, a5, a6, a7; };
struct R8 { unsigned short v0, v1, v2, v3, v4, v5, v6, v7; };
struct W3 { float x, y, z; };

template <unsigned SIZE>
__device__ __forceinline__ I8 idx8m(float p01x, float p01y, float p01z, int res, W3& fr)
{
    const float rm1 = (float)(res - 1);
    float xx = p01x * rm1, yy = p01y * rm1, zz = p01z * rm1;
    const float cmax = (float)(res - 2);
    float fx = fminf(fmaxf(floorf(xx), 0.0f), cmax);
    float fy = fminf(fmaxf(floorf(yy), 0.0f), cmax);
    float fz = fminf(fmaxf(floorf(zz), 0.0f), cmax);
    fr.x = xx - fx; fr.y = yy - fy; fr.z = zz - fz;
    const unsigned ix = (unsigned)(int)fx;
    const unsigned iy = (unsigned)(int)fy;
    const unsigned iz = (unsigned)(int)fz;
    const unsigned hy0 = iy * 2654435761u, hy1 = hy0 + 2654435761u;
    const unsigned hz0 = iz * 805459861u,  hz1 = hz0 + 805459861u;
    I8 o;
    o.a0 = (ix ^ hy0 ^ hz0) % SIZE;        o.a1 = (ix ^ hy0 ^ hz1) % SIZE;
    o.a2 = (ix ^ hy1 ^ hz0) % SIZE;        o.a3 = (ix ^ hy1 ^ hz1) % SIZE;
    o.a4 = ((ix+1u) ^ hy0 ^ hz0) % SIZE;   o.a5 = ((ix+1u) ^ hy0 ^ hz1) % SIZE;
    o.a6 = ((ix+1u) ^ hy1 ^ hz0) % SIZE;   o.a7 = ((ix+1u) ^ hy1 ^ hz1) % SIZE;
    return o;
}

__device__ __forceinline__ R8 gather8(const unsigned short* __restrict__ t, I8 o)
{
    R8 r;
    r.v0 = t[o.a0]; r.v1 = t[o.a1]; r.v2 = t[o.a2]; r.v3 = t[o.a3];
    r.v4 = t[o.a4]; r.v5 = t[o.a5]; r.v6 = t[o.a6]; r.v7 = t[o.a7];
    return r;
}

__device__ __forceinline__ float acc8(R8 r, W3 f)
{
    const float wx1 = f.x, wx0 = 1.0f - f.x;
    const float wy1 = f.y, wy0 = 1.0f - f.y;
    const float wz1 = f.z, wz0 = 1.0f - f.z;
    const float w00 = wy0 * wz0, w01 = wy0 * wz1;
    const float w10 = wy1 * wz0, w11 = wy1 * wz1;
    const float sx0 = bf16_to_f32(r.v0) * w00 + bf16_to_f32(r.v1) * w01
                    + bf16_to_f32(r.v2) * w10 + bf16_to_f32(r.v3) * w11;
    const float sx1 = bf16_to_f32(r.v4) * w00 + bf16_to_f32(r.v5) * w01
                    + bf16_to_f32(r.v6) * w10 + bf16_to_f32(r.v7) * w11;
    return wx0 * sx0 + wx1 * sx1;
}

// Merged x-pair LOD. MODE: 0 = pow2 2^19 (mask), 1 = mod 85184 (even size).
// Even x-pair base -> hashes {h, h^1}; E = reduced(h&~1) is EVEN in both
// modes -> aligned dword in the u16 table covers both x-corners.
// Odd-ix lanes take 4 extra exec-masked u16 loads.
template <int MODE>
__device__ __forceinline__ float lod_merged(float p01x, float p01y, float p01z,
                                            int res,
                                            const unsigned short* __restrict__ t)
{
    const float rm1 = (float)(res - 1);
    float xx = p01x * rm1, yy = p01y * rm1, zz = p01z * rm1;
    const float cmax = (float)(res - 2);
    float fx = fminf(fmaxf(floorf(xx), 0.0f), cmax);
    float fy = fminf(fmaxf(floorf(yy), 0.0f), cmax);
    float fz = fminf(fmaxf(floorf(zz), 0.0f), cmax);
    const float frx = xx - fx, fry = yy - fy, frz = zz - fz;
    const unsigned ix = (unsigned)(int)fx;
    const unsigned iy = (unsigned)(int)fy;
    const unsigned iz = (unsigned)(int)fz;

    const unsigned hy0 = iy * 2654435761u, hy1 = hy0 + 2654435761u;
    const unsigned hz0 = iz * 805459861u,  hz1 = hz0 + 805459861u;

    const unsigned h00 = ix ^ hy0 ^ hz0;
    const unsigned h01 = ix ^ hy0 ^ hz1;
    const unsigned h10 = ix ^ hy1 ^ hz0;
    const unsigned h11 = ix ^ hy1 ^ hz1;

    unsigned E00, E01, E10, E11;
    if (MODE == 0) {
        const unsigned bm = 524286u;  // (2^19-1) & ~1
        E00 = h00 & bm; E01 = h01 & bm; E10 = h10 & bm; E11 = h11 & bm;
    } else {
        E00 = (h00 & ~1u) % 85184u; E01 = (h01 & ~1u) % 85184u;
        E10 = (h10 & ~1u) % 85184u; E11 = (h11 & ~1u) % 85184u;
    }

    const unsigned* t32 = reinterpret_cast<const unsigned*>(t);  // E even, t 4B-aligned
    const unsigned p00 = t32[E00 >> 1];
    const unsigned p01 = t32[E01 >> 1];
    const unsigned p10 = t32[E10 >> 1];
    const unsigned p11 = t32[E11 >> 1];

    const bool oddx = (ix & 1u) != 0u;
    unsigned short q00 = 0, q01 = 0, q10 = 0, q11 = 0;
    if (oddx) {
        const unsigned g = ix + 1u;
        if (MODE == 0) {
            const unsigned m = 524287u;
            q00 = t[(g ^ hy0 ^ hz0) & m]; q01 = t[(g ^ hy0 ^ hz1) & m];
            q10 = t[(g ^ hy1 ^ hz0) & m]; q11 = t[(g ^ hy1 ^ hz1) & m];
        } else {
            q00 = t[(g ^ hy0 ^ hz0) % 85184u]; q01 = t[(g ^ hy0 ^ hz1) % 85184u];
            q10 = t[(g ^ hy1 ^ hz0) % 85184u]; q11 = t[(g ^ hy1 ^ hz1) % 85184u];
        }
    }

    const unsigned s00 = h00 & 1u, s01 = h01 & 1u, s10 = h10 & 1u, s11 = h11 & 1u;
    const float a00 = bf16_to_f32((unsigned short)(s00 ? (p00 >> 16) : (p00 & 0xffffu)));
    const float a01 = bf16_to_f32((unsigned short)(s01 ? (p01 >> 16) : (p01 & 0xffffu)));
    const float a10 = bf16_to_f32((unsigned short)(s10 ? (p10 >> 16) : (p10 & 0xffffu)));
    const float a11 = bf16_to_f32((unsigned short)(s11 ? (p11 >> 16) : (p11 & 0xffffu)));
    const float b00 = bf16_to_f32(oddx ? q00 : (unsigned short)(s00 ? (p00 & 0xffffu) : (p00 >> 16)));
    const float b01 = bf16_to_f32(oddx ? q01 : (unsigned short)(s01 ? (p01 & 0xffffu) : (p01 >> 16)));
    const float b10 = bf16_to_f32(oddx ? q10 : (unsigned short)(s10 ? (p10 & 0xffffu) : (p10 >> 16)));
    const float b11 = bf16_to_f32(oddx ? q11 : (unsigned short)(s11 ? (p11 & 0xffffu) : (p11 >> 16)));

    const float wx1 = frx, wx0 = 1.0f - frx;
    const float wy1 = fry, wy0 = 1.0f - fry;
    const float wz1 = frz, wz0 = 1.0f - frz;
    const float w00 = wy0 * wz0, w01 = wy0 * wz1;
    const float w10 = wy1 * wz0, w11 = wy1 * wz1;
    const float sx0 = a00 * w00 + a01 * w01 + a10 * w10 + a11 * w11;
    const float sx1 = b00 * w00 + b01 * w01 + b10 * w10 + b11 * w11;
    return wx0 * sx0 + wx1 * sx1;
}

// prep: convert LOD2..7 table prefixes to bf16 in ws
__global__ __launch_bounds__(1024)
void HashGrid_convert_kernel(const float* __restrict__ codebook,
                             unsigned short* __restrict__ ws)
{
    const int lod = blockIdx.y;  // 0..5 -> LOD2..7
    const int sizes[6] = {85184, 357911, 524288, 524288, 524288, 524288};
    const unsigned offs[6] = {WO2, WO3, WO4, WO5, WO6, WO7};
    const int idx = blockIdx.x * 1024 + threadIdx.x;
    if (idx < sizes[lod])
        ws[offs[lod] + idx] = f32_to_bf16_rne(codebook[(unsigned)(lod + 2) * CB_STRIDE + idx]);
}

__global__ __launch_bounds__(1024, 4)
void HashGrid_88278757802387_kernel(const float* __restrict__ pts,
                                    const float* __restrict__ codebook,
                                    const unsigned short* __restrict__ ws,
                                    float* __restrict__ out,
                                    int n, int res7)
{
    __shared__ unsigned short sm[S0 + S1];  // 49.2 KB
    for (int j = threadIdx.x; j < S0 + S1; j += 1024)
        sm[j] = f32_to_bf16_rne(j < S0 ? codebook[j] : codebook[CB_STRIDE + (j - S0)]);
    __syncthreads();

    const int i = blockIdx.x * 1024 + threadIdx.x;
    if (i >= n) return;

    const float p01x = pts[3 * i + 0] * 0.5f + 0.5f;
    const float p01y = pts[3 * i + 1] * 0.5f + 0.5f;
    const float p01z = pts[3 * i + 2] * 0.5f + 0.5f;

    // LOD3 (odd size, unmergeable): issue its 8 u16 gathers early
    W3 fB, fL0, fL1;
    I8 oB = idx8m<357911u>(p01x, p01y, p01z, 71, fB);
    R8 rB = gather8(ws + WO3, oB);

    // merged x-pair LODs (6 avg requests each, zero extra footprint)
    float acc = lod_merged<1>(p01x, p01y, p01z, 44,   ws + WO2);
    acc      += lod_merged<0>(p01x, p01y, p01z, 116,  ws + WO4);
    acc      += lod_merged<0>(p01x, p01y, p01z, 191,  ws + WO5);
    acc      += lod_merged<0>(p01x, p01y, p01z, 313,  ws + WO6);
    acc      += lod_merged<0>(p01x, p01y, p01z, res7, ws + WO7);

    // LDS LODs (off the TCP path)
    I8 oL0 = idx8m<4913u >(p01x, p01y, p01z, 17, fL0);
    I8 oL1 = idx8m<19683u>(p01x, p01y, p01z, 27, fL1);
    R8 rL0 = gather8(sm, oL0);
    R8 rL1 = gather8(sm + S0, oL1);
    acc += acc8(rL0, fL0) + acc8(rL1, fL1);

    // consume LOD3
    acc += acc8(rB, fB);

    out[i] = acc;
}

// fallback (no ws): per-LOD f32 path straight from codebook
__global__ __launch_bounds__(1024, 4)
void HashGrid_fallback_kernel(const float* __restrict__ pts,
                              const float* __restrict__ codebook,
                              float* __restrict__ out,
                              int n, int res7)
{
    const int i = blockIdx.x * 1024 + threadIdx.x;
    if (i >= n) return;
    const float p01x = pts[3 * i + 0] * 0.5f + 0.5f;
    const float p01y = pts[3 * i + 1] * 0.5f + 0.5f;
    const float p01z = pts[3 * i + 2] * 0.5f + 0.5f;
    float acc = 0.0f;
    const int      reslist[8]  = {17, 27, 44, 71, 116, 191, 313, res7};
    const unsigned sizelist[8] = {4913u, 19683u, 85184u, 357911u, 524288u, 524288u, 524288u, 524288u};
    for (int l = 0; l < 8; ++l) {
        const int res = reslist[l];
        const unsigned size = sizelist[l];
        const float rm1 = (float)(res - 1);
        float xx = p01x * rm1, yy = p01y * rm1, zz = p01z * rm1;
        float fx = fminf(fmaxf(floorf(xx), 0.0f), (float)(res - 2));
        float fy = fminf(fmaxf(floorf(yy), 0.0f), (float)(res - 2));
        float fz = fminf(fmaxf(floorf(zz), 0.0f), (float)(res - 2));
        const float frx = xx - fx, fry = yy - fy, frz = zz - fz;
        const unsigned ix = (unsigned)(int)fx, iy = (unsigned)(int)fy, iz = (unsigned)(int)fz;
        const unsigned hy0 = iy * 2654435761u, hy1 = hy0 + 2654435761u;
        const unsigned hz0 = iz * 805459861u,  hz1 = hz0 + 805459861u;
        const unsigned o0 = (ix ^ hy0 ^ hz0) % size,      o1 = (ix ^ hy0 ^ hz1) % size;
        const unsigned o2 = (ix ^ hy1 ^ hz0) % size,      o3 = (ix ^ hy1 ^ hz1) % size;
        const unsigned o4 = ((ix+1u) ^ hy0 ^ hz0) % size, o5 = ((ix+1u) ^ hy0 ^ hz1) % size;
        const unsigned o6 = ((ix+1u) ^ hy1 ^ hz0) % size, o7 = ((ix+1u) ^ hy1 ^ hz1) % size;
        const float* tab = codebook + (unsigned)l * CB_STRIDE;
        const float wx1 = frx, wx0 = 1.0f - frx;
        const float wy1 = fry, wy0 = 1.0f - fry;
        const float wz1 = frz, wz0 = 1.0f - frz;
        const float w00 = wy0*wz0, w01 = wy0*wz1, w10 = wy1*wz0, w11 = wy1*wz1;
        acc += wx0 * (tab[o0]*w00 + tab[o1]*w01 + tab[o2]*w10 + tab[o3]*w11)
             + wx1 * (tab[o4]*w00 + tab[o5]*w01 + tab[o6]*w10 + tab[o7]*w11);
    }
    out[i] = acc;
}

extern "C" void kernel_launch(void* const* d_in, const int* in_sizes, int n_in,
                              void* d_out, int out_size, void* d_ws, size_t ws_size,
                              hipStream_t stream)
{
    const float* pts      = (const float*)d_in[0];
    const float* codebook = (const float*)d_in[1];
    float* out            = (float*)d_out;
    const int n = in_sizes[0] / 3;

    // numpy-matching LOD7 resolution (16*b^7 sits ~1e-12 from 512.0)
    const double b = exp((log(512.0) - log(16.0)) / 7.0);
    const int res7 = (int)(1.0 + floor(16.0 * pow(b, 7.0)));

    const bool use_ws = (d_ws != nullptr) && (ws_size >= WS_NEED_BYTES);
    const int blocks = (n + 1023) / 1024;

    if (use_ws) {
        unsigned short* ws = (unsigned short*)d_ws;
        hipLaunchKernelGGL(HashGrid_convert_kernel, dim3(512, 6), dim3(1024),
                           0, stream, codebook, ws);
        hipLaunchKernelGGL(HashGrid_88278757802387_kernel, dim3(blocks), dim3(1024),
                           0, stream, pts, codebook, ws, out, n, res7);
    } else {
        hipLaunchKernelGGL(HashGrid_fallback_kernel, dim3(blocks), dim3(1024),
                           0, stream, pts, codebook, out, n, res7);
    }
}